// Round 5
// baseline (210.264 us; speedup 1.0000x reference)
//
#include <hip/hip_runtime.h>
#include <math.h>

// HomoAttention, two-pass streaming restructure (R5).
// Sizes: B*N=2048, K=64, F=8, E=32, D=256. neigh = 128 MB (fits L3).
// Pass A: one wave per (bn,k): score[bn,k,f] = dot(z,x)/(max(|z|,eps)*max(|x|,eps)),
//         also zinv[bn,k,f]=1/max(|z|,eps). Pure HBM read stream, ~16 VGPR,
//         cached loads so neigh allocates in L3 for pass B.
// Pass B: per bn: softmax over k from d_ws scores (zinv folded into weight),
//         then re-stream neigh[bn] from L3 with immediate u += w*z (no zr[16]
//         retention, no long per-block tail — the R1-R4 monolith's suspects).

#define NF 8
#define DD 256
#define KK 64

typedef float f4 __attribute__((ext_vector_type(4)));

__global__ __launch_bounds__(256)
void scores_kernel(const float* __restrict__ features,
                   const float* __restrict__ neigh,
                   float* __restrict__ scores,   // [bn][k][f]
                   float* __restrict__ zinv)     // [bn][k][f]
{
    const int gw  = (blockIdx.x * 256 + threadIdx.x) >> 6;  // bn*64 + k
    const int l   = threadIdx.x & 63;
    const int f   = l >> 3;
    const int sub = l & 7;
    const int bn  = gw >> 6;

    const f4 z = ((const f4*)(neigh    + (size_t)gw * DD))[l];  // coalesced 1KB/wave
    const f4 x = ((const f4*)(features + (size_t)bn * DD))[l];  // L2/L3-hot (2MB total)

    float zss = z.x*z.x + z.y*z.y + z.z*z.z + z.w*z.w;
    float xss = x.x*x.x + x.y*x.y + x.z*x.z + x.w*x.w;
    float dot = z.x*x.x + z.y*x.y + z.z*x.z + z.w*x.w;
#pragma unroll
    for (int s = 1; s <= 4; s <<= 1) {
        zss += __shfl_xor(zss, s);
        xss += __shfl_xor(xss, s);
        dot += __shfl_xor(dot, s);
    }
    const float zn = fmaxf(sqrtf(zss), 1e-12f);
    const float xn = fmaxf(sqrtf(xss), 1e-12f);
    if (sub == 0) scores[(size_t)gw * NF + f] = dot / (zn * xn);
    if (sub == 1) zinv  [(size_t)gw * NF + f] = 1.0f / zn;
}

__global__ __launch_bounds__(256)
void attend_kernel(const float* __restrict__ neigh,
                   const float* __restrict__ scores,
                   const float* __restrict__ zinv,
                   float* __restrict__ out)
{
    const int bn = blockIdx.x;
    const int t  = threadIdx.x;
    const int l  = t & 63;
    const int tg = t >> 6;
    const int f  = l >> 3;

    __shared__ float a_s[KK * NF];    // 2 KB scores
    __shared__ float zi_s[KK * NF];   // 2 KB 1/|z|
    __shared__ f4    part[4][64];     // 4 KB cross-wave partials

    const float* sp = scores + (size_t)bn * (KK * NF);
    const float* zp = zinv   + (size_t)bn * (KK * NF);
    a_s [t]       = sp[t];
    a_s [t + 256] = sp[t + 256];
    zi_s[t]       = zp[t];
    zi_s[t + 256] = zp[t + 256];
    __syncthreads();

    // softmax over k for this thread's facet (broadcast LDS reads)
    float m = -1e30f;
#pragma unroll 8
    for (int k = 0; k < KK; ++k) m = fmaxf(m, a_s[k * NF + f]);
    float denom = 0.0f;
#pragma unroll 8
    for (int k = 0; k < KK; ++k) denom += __expf(a_s[k * NF + f] - m);
    const float inv = 1.0f / denom;

    // per-k weight with 1/|z| folded in; this wave handles k = i*4 + tg
    float wk[16];
#pragma unroll
    for (int i = 0; i < 16; ++i) {
        const int k = i * 4 + tg;
        wk[i] = __expf(a_s[k * NF + f] - m) * inv * zi_s[k * NF + f];
    }

    // stream z from L3 (warmed by pass A), immediate consumption
    const float* zrow = neigh + (size_t)bn * (KK * DD);
    f4 u = (f4)(0.f, 0.f, 0.f, 0.f);
#pragma unroll
    for (int i = 0; i < 16; ++i) {
        const int k = i * 4 + tg;
        const f4 zv = ((const f4*)(zrow + k * DD))[l];
        u += wk[i] * zv;
    }
    part[tg][l] = u;
    __syncthreads();

    if (tg == 0) {
        f4 r = part[0][l] + part[1][l] + part[2][l] + part[3][l];
        ((f4*)(out + (size_t)bn * DD))[l] = r;
    }
}

extern "C" void kernel_launch(void* const* d_in, const int* in_sizes, int n_in,
                              void* d_out, int out_size, void* d_ws, size_t ws_size,
                              hipStream_t stream) {
    const float* features = (const float*)d_in[0];
    const float* neigh    = (const float*)d_in[1];
    float* out            = (float*)d_out;

    float* scores = (float*)d_ws;                       // 2048*64*8*4 = 4 MB
    float* zinvp  = scores + (size_t)2048 * KK * NF;    // next 4 MB

    const int BN = in_sizes[0] / DD;                    // 2048
    const int nwavesA = BN * KK;                        // 131072 waves
    scores_kernel<<<nwavesA / 4, 256, 0, stream>>>(features, neigh, scores, zinvp);
    attend_kernel<<<BN, 256, 0, stream>>>(neigh, scores, zinvp, out);
}

// Round 6
// 186.849 us; speedup vs baseline: 1.1253x; 1.1253x over previous
//
#include <hip/hip_runtime.h>
#include <math.h>

// HomoAttention monolith (R6). B*N=2048 blocks? -> now 2048 blocks of 512 thr.
// Per (b,n): x[F=8][E=32], z[K=64][F][E]; L2-normalize over E; a[k][f]=cos sim;
// softmax over k; u = sum_k a*zn. neigh = 134 MB read-once (nt), out 2 MB (nt).
//
// R6 changes vs R4 (best, 195.9us):
//  - 512-thread blocks: 8 waves/block, zr[8] (32 VGPR) instead of zr[16] (64)
//    -> higher occupancy, same per-CU bytes in flight. Probe: if kernel was
//    latency/occupancy-limited this wins ~5-10us; if flat, we're at the
//    harness-stream floor (fill 77us + restore ~50us are fixed per iteration).
//  - softmax WITHOUT max-subtraction: scores are cosines in [-1,1] (post-
//    normalization Cauchy-Schwarz), exp in [0.37,2.72] -- shift unneeded.
//    Saves 64 LDS reads + 64 fmax per thread of serial tail.

#define NF 8
#define DD 256
#define KK 64

typedef float f4 __attribute__((ext_vector_type(4)));

__global__ __launch_bounds__(512)
void homo_attn_kernel(const float* __restrict__ features,
                      const float* __restrict__ neigh,
                      float* __restrict__ out)
{
    const int bn = blockIdx.x;
    const int t  = threadIdx.x;
    const int l  = t & 63;   // lane
    const int tg = t >> 6;   // wave 0..7
    const int f  = l >> 3;   // facet
    const int sub = l & 7;

    const float* xp = features + (size_t)bn * DD;
    const float* zp = neigh    + (size_t)bn * (KK * DD);

    // ---- batch x load + this wave's 8 z-row loads (all in flight) ----
    f4 xv = ((const f4*)xp)[l];
    f4 zr[8];
#pragma unroll
    for (int i = 0; i < 8; ++i) {
        const int k = i * 8 + tg;
        zr[i] = __builtin_nontemporal_load(((const f4*)(zp + k * DD)) + l);
    }
    __builtin_amdgcn_sched_barrier(0);

    // ---- normalize x fragment ----
    float ss = xv.x*xv.x + xv.y*xv.y + xv.z*xv.z + xv.w*xv.w;
    ss += __shfl_xor(ss, 1);
    ss += __shfl_xor(ss, 2);
    ss += __shfl_xor(ss, 4);
    float xs = 1.0f / fmaxf(sqrtf(ss), 1e-12f);
    xv *= xs;

    __shared__ float a_s[KK * NF];   // 2 KB scores
    __shared__ f4    part[8][64];    // 8 KB cross-wave partials

    // ---- normalize z, cosine scores ----
#pragma unroll
    for (int i = 0; i < 8; ++i) {
        const int k = i * 8 + tg;
        f4 z = zr[i];
        float zss = z.x*z.x + z.y*z.y + z.z*z.z + z.w*z.w;
        zss += __shfl_xor(zss, 1);
        zss += __shfl_xor(zss, 2);
        zss += __shfl_xor(zss, 4);
        float zs = 1.0f / fmaxf(sqrtf(zss), 1e-12f);
        z *= zs;
        zr[i] = z;
        float d = z.x*xv.x + z.y*xv.y + z.z*xv.z + z.w*xv.w;
        d += __shfl_xor(d, 1);
        d += __shfl_xor(d, 2);
        d += __shfl_xor(d, 4);
        if (sub == 0) a_s[k * NF + f] = d;
    }
    __syncthreads();

    // ---- softmax over k (no max-shift: |a|<=1) ----
    float denom = 0.0f;
#pragma unroll 8
    for (int k = 0; k < KK; ++k) denom += __expf(a_s[k * NF + f]);
    const float inv = 1.0f / denom;

    // ---- weighted partial sum over this wave's 8 k's ----
    f4 u = (f4)(0.f, 0.f, 0.f, 0.f);
#pragma unroll
    for (int i = 0; i < 8; ++i) {
        const int k = i * 8 + tg;
        u += (__expf(a_s[k * NF + f]) * inv) * zr[i];
    }
    part[tg][l] = u;
    __syncthreads();

    // ---- combine 8 wave partials, store ----
    if (tg == 0) {
        f4 r = (part[0][l] + part[1][l]) + (part[2][l] + part[3][l])
             + (part[4][l] + part[5][l]) + (part[6][l] + part[7][l]);
        __builtin_nontemporal_store(r, ((f4*)(out + (size_t)bn * DD)) + l);
    }
}

extern "C" void kernel_launch(void* const* d_in, const int* in_sizes, int n_in,
                              void* d_out, int out_size, void* d_ws, size_t ws_size,
                              hipStream_t stream) {
    const float* features = (const float*)d_in[0];
    const float* neigh    = (const float*)d_in[1];
    float* out            = (float*)d_out;
    const int BN = in_sizes[0] / DD;   // 128*16 = 2048
    homo_attn_kernel<<<BN, 512, 0, stream>>>(features, neigh, out);
}